// Round 9
// baseline (30.161 us; speedup 1.0000x reference)
//
#include <hip/hip_runtime.h>
#include <math.h>

// SegmentTreeAttention — MI355X (gfx950), round 9.
// B=16, S=8192, D=64, N=32, LEVELS=5. f32 in/out. valid_lens per-batch.
//
// r6 (data prefetch), r7 (staging split), r8 (LDS volume) all ~neutral ->
// the binding constraint is the serial resolve chain:
//   cond -> mid -> ds_read -> dot -> DPP -> exp -> IEEE div -> cond
// This round SPECULATES THE COMPUTE: at level lev, both level-(lev+1)
// children (mid +/- step) get their dots, reductions, masks and sigmoids
// computed before cond(lev) resolves; resolution is then just scalar
// cndmask selects (~20 cyc/level). ~1.9x VALU, but it's all independent
// ILP that overlaps. Taken-path ops/values are EXACTLY r5's -> output
// bit-identical (absmax 0.015625).
//  - 1 query per 8-lane group (QPB=32) to hold VGPR ~90.
//  - Keeps: DPP reduce, r6 clamp identity, deferred Pv gather (r5 tail),
//    q-load hoist, no launch-bounds cap (r3 lesson).

#define SEG_N   32
#define DIM     64
#define LEVELS  5
#define QPB     32      // queries per block (1 per 8-lane group)
#define THREADS 256
#define PAD     68      // LDS row stride in dwords

#define DPP_QUAD_XOR1   0xB1    // quad_perm [1,0,3,2]
#define DPP_QUAD_XOR2   0x4E    // quad_perm [2,3,0,1]
#define DPP_ROW_HMIRROR 0x141   // row_half_mirror (lane p -> 7-p within 8)

template <int CTRL>
__device__ __forceinline__ float dpp_xadd(float v) {
    const int s = __builtin_amdgcn_update_dpp(0, __float_as_int(v), CTRL, 0xf, 0xf, true);
    return v + __int_as_float(s);
}

// 8-lane group sum, all lanes get the bit-identical total.
__device__ __forceinline__ float group8_sum(float v) {
    v = dpp_xadd<DPP_QUAD_XOR1>(v);
    v = dpp_xadd<DPP_QUAD_XOR2>(v);
    v = dpp_xadd<DPP_ROW_HMIRROR>(v);
    return v;
}

__device__ __forceinline__ float4 f4sub(const float4 a, const float4 b) {
    return make_float4(a.x - b.x, a.y - b.y, a.z - b.z, a.w - b.w);
}
__device__ __forceinline__ float4 sel4(bool c, const float4 a, const float4 b) {
    return make_float4(c ? a.x : b.x, c ? a.y : b.y, c ? a.z : b.z, c ? a.w : b.w);
}
__device__ __forceinline__ float dot4(const float4 a, const float4 b) {
    return a.x * b.x + a.y * b.y + a.z * b.z + a.w * b.w;
}
__device__ __forceinline__ void fma4(float4& acc, const float4 hi, const float4 lo, float w) {
    acc.x = fmaf(hi.x - lo.x, w, acc.x);
    acc.y = fmaf(hi.y - lo.y, w, acc.y);
    acc.z = fmaf(hi.z - lo.z, w, acc.z);
    acc.w = fmaf(hi.w - lo.w, w, acc.w);
}

// masked sigmoid, exact formula from all passing rounds (IEEE div)
__device__ __forceinline__ float msig(bool ok, float d) {
    const float s = ok ? d : 0.0f;
    return 1.0f / (1.0f + __expf(-s));
}

__global__ __launch_bounds__(THREADS) void segtree_attn_kernel(
    const float* __restrict__ q,
    const float* __restrict__ keys,
    const float* __restrict__ values,
    const int*   __restrict__ vlen,
    float*       __restrict__ out,
    int S)
{
    __shared__ float Pk[SEG_N * PAD];
    __shared__ float Pv[SEG_N * PAD];

    const int b = blockIdx.y;
    const int t = threadIdx.x;
    const int g = t >> 3;           // query group within block (0..31)
    const int u = t & 7;            // lane within group
    const int c = u * 8;            // column base (2x float4)

    const int s = blockIdx.x * QPB + g;

    // ---- q loads hoisted: latency hides under staging + barrier ----
    const float* qp = q + ((size_t)b * S + s) * DIM + c;
    const float4 q0 = *(const float4*)qp;
    const float4 q1 = *(const float4*)(qp + 4);

    // ---- Stage prefix sums into LDS: P[0]=0, P[m]=sum_{l=1..m} x[l] ----
    if (t < 2 * DIM) {
        const int col = t & (DIM - 1);
        const float* src = ((t < DIM) ? keys : values) + (size_t)b * SEG_N * DIM + col;
        float* dst = (t < DIM) ? Pk : Pv;
        float acc = 0.0f;
        dst[col] = 0.0f;
        #pragma unroll
        for (int row = 1; row < SEG_N; ++row) {
            acc += src[row * DIM];
            dst[row * PAD + col] = acc;
        }
    }
    const int n = vlen[b];          // block-uniform (valid_lens is [B])
    __syncthreads();

    const int hnc = max(min(n - 1, SEG_N - 1), 0);
    const float scale[LEVELS] = {0.0625f, 0.125f, 0.25f, 0.5f, 1.0f};

    // ---- prologue: level-0 node (l=1, r=32, mid=16) computed directly ----
    int mid = 16, l = 1, r = SEG_N;
    int rowA = 0, rowR = hnc;
    int cm = min(16, hnc);

    float4 pkA0 = make_float4(0.f,0.f,0.f,0.f), pkA1 = make_float4(0.f,0.f,0.f,0.f);
    float4 pkR0 = *(const float4*)&Pk[hnc * PAD + c];
    float4 pkR1 = *(const float4*)&Pk[hnc * PAD + c + 4];
    float4 pkM0 = *(const float4*)&Pk[cm * PAD + c];
    float4 pkM1 = *(const float4*)&Pk[cm * PAD + c + 4];

    bool okL = (min(mid, n - 1) >= l);
    bool okR = (min(r,   n - 1) >= mid + 1);
    float dL = dot4(q0, f4sub(pkM0, pkA0)) + dot4(q1, f4sub(pkM1, pkA1));
    float dR = dot4(q0, f4sub(pkR0, pkM0)) + dot4(q1, f4sub(pkR1, pkM1));
    float ls = msig(okL, group8_sum(dL));
    float rs = msig(okR, group8_sum(dR));

    float wq[LEVELS];
    int   rows[LEVELS];             // hi | lo<<8

    #pragma unroll
    for (int lev = 0; lev < LEVELS; ++lev) {
        const int step = 8 >> lev;

        // ---- speculate BOTH children of the current node (lev+1) ----
        float lsLo = 0.f, rsLo = 0.f, lsHi = 0.f, rsHi = 0.f;
        bool okLLo = false, okRLo = false, okLHi = false, okRHi = false;
        int midLo = 0, midHi = 0, cmLo = 0, cmHi = 0;
        float4 pkLo0, pkLo1, pkHi0, pkHi1;
        if (lev < LEVELS - 1) {
            midLo = mid - step; midHi = mid + step;
            cmLo = min(midLo, hnc); cmHi = min(midHi, hnc);
            pkLo0 = *(const float4*)&Pk[cmLo * PAD + c];
            pkLo1 = *(const float4*)&Pk[cmLo * PAD + c + 4];
            pkHi0 = *(const float4*)&Pk[cmHi * PAD + c];
            pkHi1 = *(const float4*)&Pk[cmHi * PAD + c + 4];

            // child-lo = (l, mid), mid' = midLo
            float dLLo = dot4(q0, f4sub(pkLo0, pkA0)) + dot4(q1, f4sub(pkLo1, pkA1));
            float dRLo = dot4(q0, f4sub(pkM0,  pkLo0)) + dot4(q1, f4sub(pkM1,  pkLo1));
            // child-hi = (mid+1, r), mid' = midHi
            float dLHi = dot4(q0, f4sub(pkHi0, pkM0)) + dot4(q1, f4sub(pkHi1, pkM1));
            float dRHi = dot4(q0, f4sub(pkR0,  pkHi0)) + dot4(q1, f4sub(pkR1,  pkHi1));

            dLLo = group8_sum(dLLo);
            dRLo = group8_sum(dRLo);
            dLHi = group8_sum(dLHi);
            dRHi = group8_sum(dRHi);

            okLLo = (min(midLo, n - 1) >= l);
            okRLo = (min(mid,   n - 1) >= midLo + 1);
            okLHi = (min(midHi, n - 1) >= mid + 1);
            okRHi = (min(r,     n - 1) >= midHi + 1);

            lsLo = msig(okLLo, dLLo);
            rsLo = msig(okRLo, dRLo);
            lsHi = msig(okLHi, dLHi);
            rsHi = msig(okRHi, dRHi);
        }

        // ---- resolve current level (short scalar chain) ----
        const bool cond = (ls >= rs);

        const bool  oksel = cond ? okR : okL;
        const float wsel  = cond ? rs : ls;
        wq[lev] = oksel ? (wsel * scale[lev]) : 0.0f;   // pow2 scale: exact

        const int hi = cond ? rowR : cm;
        const int lo = cond ? mid  : rowA;
        rows[lev] = hi | (lo << 8);

        // ---- state update via selects (all values already computed) ----
        rowA = cond ? rowA : mid;
        rowR = cond ? cm   : rowR;
        pkA0 = sel4(cond, pkA0, pkM0); pkA1 = sel4(cond, pkA1, pkM1);
        pkR0 = sel4(cond, pkM0, pkR0); pkR1 = sel4(cond, pkM1, pkR1);
        l = cond ? l   : mid + 1;
        r = cond ? mid : r;

        if (lev < LEVELS - 1) {
            mid = cond ? midLo : midHi;
            cm  = cond ? cmLo  : cmHi;
            pkM0 = sel4(cond, pkLo0, pkHi0);
            pkM1 = sel4(cond, pkLo1, pkHi1);
            ls = cond ? lsLo : lsHi;
            rs = cond ? rsLo : rsHi;
            okL = cond ? okLLo : okLHi;
            okR = cond ? okRLo : okRHi;
        }
    }

    // ---- deferred value gather: ans = sum_lev w * (Pv[hi] - Pv[lo]) ----
    float4 a0 = make_float4(0.f,0.f,0.f,0.f), a1 = make_float4(0.f,0.f,0.f,0.f);
    #pragma unroll
    for (int lev = 0; lev < LEVELS; ++lev) {
        const int pk = rows[lev];
        const int hiR = pk & 0xFF, loR = (pk >> 8) & 0xFF;
        const float4 h0 = *(const float4*)&Pv[hiR * PAD + c];
        const float4 h1 = *(const float4*)&Pv[hiR * PAD + c + 4];
        const float4 l0 = *(const float4*)&Pv[loR * PAD + c];
        const float4 l1 = *(const float4*)&Pv[loR * PAD + c + 4];
        fma4(a0, h0, l0, wq[lev]);
        fma4(a1, h1, l1, wq[lev]);
    }

    float* op = out + ((size_t)b * S + s) * DIM + c;
    *(float4*)op       = a0;
    *(float4*)(op + 4) = a1;
}

extern "C" void kernel_launch(void* const* d_in, const int* in_sizes, int n_in,
                              void* d_out, int out_size, void* d_ws, size_t ws_size,
                              hipStream_t stream) {
    const float* q    = (const float*)d_in[0];
    const float* keys = (const float*)d_in[1];
    const float* vals = (const float*)d_in[2];
    const int*   vl   = (const int*)d_in[3];
    float* out = (float*)d_out;

    const int B = in_sizes[3];                 // 16
    const int S = in_sizes[0] / (B * DIM);     // 8192

    dim3 grid(S / QPB, B);
    segtree_attn_kernel<<<grid, THREADS, 0, stream>>>(q, keys, vals, vl, out, S);
}

// Round 10
// 24.608 us; speedup vs baseline: 1.2257x; 1.2257x over previous
//
#include <hip/hip_runtime.h>
#include <math.h>

// SegmentTreeAttention — MI355X (gfx950), round 10.
// B=16, S=8192, D=64, N=32, LEVELS=5. f32 in/out. valid_lens per-batch.
//
// Diagnosis: VALU-instruction-bound (r1: VALUBusy 60%, all else idle;
// r6/r7/r8/r9 exonerated LDS latency/staging/LDS-volume/cond-chain).
// Biggest VALU block = sigmoid cluster (4 IEEE divs/thread/level).
// Changes vs r5/r7 base (26.5us):
//  - Div-free cond: IEEE div is monotone, so (ls>=rs) == (dnL<=dnR)
//    except when dnL>dnR but both reciprocals round equal; that gray zone
//    ((dnL-dnR) < dnL*1e-6, 8x margin) is rescued with exact divs under
//    __any(gray) (P~1e-5/wave-level). cond stays BIT-EXACT.
//  - Weight via v_rcp_f32 (output-only, <=1ulp; threshold margin 8x).
//  - Gather uses packed 16+16-bit LDS BYTE offsets captured during
//    descent (no mul in gather); Pk/Pv in one shared array.
// Keeps: QPB=64, 2-query ILP, DPP reduce, clamp identity (r7/r8 HW-
// validated), deferred Pv gather, q-load hoist, no launch-bounds cap.

#define SEG_N   32
#define DIM     64
#define LEVELS  5
#define QPB     64      // queries per block
#define THREADS 256
#define PAD     68      // LDS row stride in dwords
#define PADB    (PAD * 4)

#define DPP_QUAD_XOR1   0xB1    // quad_perm [1,0,3,2]
#define DPP_QUAD_XOR2   0x4E    // quad_perm [2,3,0,1]
#define DPP_ROW_HMIRROR 0x141   // row_half_mirror (lane p -> 7-p within 8)

#if __has_builtin(__builtin_amdgcn_rcpf)
#define RCPF(x) __builtin_amdgcn_rcpf(x)
#else
#define RCPF(x) (1.0f / (x))
#endif

template <int CTRL>
__device__ __forceinline__ float dpp_xadd(float v) {
    const int s = __builtin_amdgcn_update_dpp(0, __float_as_int(v), CTRL, 0xf, 0xf, true);
    return v + __int_as_float(s);
}

// 8-lane group sum, all lanes get the bit-identical total.
__device__ __forceinline__ float group8_sum(float v) {
    v = dpp_xadd<DPP_QUAD_XOR1>(v);
    v = dpp_xadd<DPP_QUAD_XOR2>(v);
    v = dpp_xadd<DPP_ROW_HMIRROR>(v);
    return v;
}

__device__ __forceinline__ float4 f4sub(const float4 a, const float4 b) {
    return make_float4(a.x - b.x, a.y - b.y, a.z - b.z, a.w - b.w);
}
__device__ __forceinline__ float dot4(const float4 a, const float4 b) {
    return a.x * b.x + a.y * b.y + a.z * b.z + a.w * b.w;
}
__device__ __forceinline__ void fma4(float4& acc, const float4 hi, const float4 lo, float w) {
    acc.x = fmaf(hi.x - lo.x, w, acc.x);
    acc.y = fmaf(hi.y - lo.y, w, acc.y);
    acc.z = fmaf(hi.z - lo.z, w, acc.z);
    acc.w = fmaf(hi.w - lo.w, w, acc.w);
}

__global__ __launch_bounds__(THREADS) void segtree_attn_kernel(
    const float* __restrict__ q,
    const float* __restrict__ keys,
    const float* __restrict__ values,
    const int*   __restrict__ vlen,
    float*       __restrict__ out,
    int S)
{
    __shared__ float P[2][SEG_N * PAD];   // P[0]=Pk, P[1]=Pv (adjacent)

    const int b = blockIdx.y;
    const int t = threadIdx.x;
    const int g = t >> 3;           // query group within block (0..31)
    const int u = t & 7;            // lane within group
    const int c = u * 8;            // column base (2x float4)
    const int c4 = c * 4;           // byte offset of column base

    const int sA = blockIdx.x * QPB + g;
    const int sB = sA + 32;

    // ---- q loads hoisted: latency hides under staging + barrier ----
    const float* qpA = q + ((size_t)b * S + sA) * DIM + c;
    const float* qpB = q + ((size_t)b * S + sB) * DIM + c;
    const float4 qA0 = *(const float4*)qpA;
    const float4 qA1 = *(const float4*)(qpA + 4);
    const float4 qB0 = *(const float4*)qpB;
    const float4 qB1 = *(const float4*)(qpB + 4);

    // ---- Stage prefix sums into LDS: P[0]=0, P[m]=sum_{l=1..m} x[l] ----
    if (t < 2 * DIM) {
        const int col = t & (DIM - 1);
        const float* src = ((t < DIM) ? keys : values) + (size_t)b * SEG_N * DIM + col;
        float* dst = (t < DIM) ? P[0] : P[1];
        float acc = 0.0f;
        dst[col] = 0.0f;
        #pragma unroll
        for (int row = 1; row < SEG_N; ++row) {
            acc += src[row * DIM];
            dst[row * PAD + col] = acc;
        }
    }
    const int n = vlen[b];          // block-uniform (valid_lens is [B])
    __syncthreads();

    const int hnc = max(min(n - 1, SEG_N - 1), 0);
    const float scale[LEVELS] = {0.0625f, 0.125f, 0.25f, 0.5f, 1.0f};
    const char* Kb = (const char*)&P[0][0];
    const char* Vb = (const char*)&P[1][0];

    // initial frontiers: P[l-1]=P[0]=0 ; P[clamp(min(r,n-1))] = P[hnc]
    const int offN = hnc * PADB + c4;
    float4 pkR_A0 = *(const float4*)(Kb + offN);
    float4 pkR_A1 = *(const float4*)(Kb + offN + 16);
    float4 pkR_B0 = pkR_A0, pkR_B1 = pkR_A1;
    float4 pkA_A0 = make_float4(0.f,0.f,0.f,0.f), pkA_A1 = make_float4(0.f,0.f,0.f,0.f);
    float4 pkA_B0 = make_float4(0.f,0.f,0.f,0.f), pkA_B1 = make_float4(0.f,0.f,0.f,0.f);

    int offA_A = c4, offR_A = offN;     // byte offsets of frontier rows
    int offA_B = c4, offR_B = offN;
    int midA = 16, midB = 16;
    int lA = 1, rA = SEG_N;
    int lB = 1, rB = SEG_N;

    float wA[LEVELS], wB[LEVELS];
    unsigned int rowsA[LEVELS], rowsB[LEVELS];   // hiOff | loOff<<16

    #pragma unroll
    for (int lev = 0; lev < LEVELS; ++lev) {
        const int step = 8 >> lev;
        const int cmA = min(midA, hnc);     // clamped row (r6 identity)
        const int cmB = min(midB, hnc);
        const int offMA = cmA * PADB + c4;
        const int offMB = cmB * PADB + c4;

        const float4 pkM_A0 = *(const float4*)(Kb + offMA);
        const float4 pkM_A1 = *(const float4*)(Kb + offMA + 16);
        const float4 pkM_B0 = *(const float4*)(Kb + offMB);
        const float4 pkM_B1 = *(const float4*)(Kb + offMB + 16);

        // subtract-then-dot (matches reference rounding structure)
        float dLA = dot4(qA0, f4sub(pkM_A0, pkA_A0)) + dot4(qA1, f4sub(pkM_A1, pkA_A1));
        float dRA = dot4(qA0, f4sub(pkR_A0, pkM_A0)) + dot4(qA1, f4sub(pkR_A1, pkM_A1));
        float dLB = dot4(qB0, f4sub(pkM_B0, pkA_B0)) + dot4(qB1, f4sub(pkM_B1, pkA_B1));
        float dRB = dot4(qB0, f4sub(pkR_B0, pkM_B0)) + dot4(qB1, f4sub(pkR_B1, pkM_B1));

        dLA = group8_sum(dLA);
        dRA = group8_sum(dRA);
        dLB = group8_sum(dLB);
        dRB = group8_sum(dRB);

        const bool okLA = (min(midA, n - 1) >= lA);
        const bool okRA = (min(rA,   n - 1) >= midA + 1);
        const bool okLB = (min(midB, n - 1) >= lB);
        const bool okRB = (min(rB,   n - 1) >= midB + 1);

        const float sLA = okLA ? dLA : 0.0f;
        const float sRA = okRA ? dRA : 0.0f;
        const float sLB = okLB ? dLB : 0.0f;
        const float sRB = okRB ? dRB : 0.0f;

        // sigmoid denominators (exact, same __expf as all passing rounds)
        const float dnLA = 1.0f + __expf(-sLA);
        const float dnRA = 1.0f + __expf(-sRA);
        const float dnLB = 1.0f + __expf(-sLB);
        const float dnRB = 1.0f + __expf(-sRB);

        // cond = (1/dnL >= 1/dnR) under IEEE rounding. Monotonicity makes
        // (dnL <= dnR) exact EXCEPT dnL>dnR with equal-rounded reciprocals;
        // conservative gray test rescues with the exact divisions.
        bool condA = (dnLA <= dnRA);
        bool condB = (dnLB <= dnRB);
        const bool grayA = (dnLA > dnRA) && ((dnLA - dnRA) < dnLA * 1e-6f);
        const bool grayB = (dnLB > dnRB) && ((dnLB - dnRB) < dnLB * 1e-6f);
        if (__any(grayA || grayB)) {        // P ~ 1e-5 per wave-level
            condA = ((1.0f / dnLA) >= (1.0f / dnRA));
            condB = ((1.0f / dnLB) >= (1.0f / dnRB));
        }

        const bool  okselA = condA ? okRA : okLA;
        const bool  okselB = condB ? okRB : okLB;
        const float wselA  = RCPF(condA ? dnRA : dnLA);  // weight: <=1ulp, output-only
        const float wselB  = RCPF(condB ? dnRB : dnLB);
        wA[lev] = okselA ? (wselA * scale[lev]) : 0.0f;  // pow2 scale: exact
        wB[lev] = okselB ? (wselB * scale[lev]) : 0.0f;

        const unsigned int hiA = condA ? offR_A : offMA;
        const unsigned int loA = condA ? offMA  : offA_A;
        const unsigned int hiB = condB ? offR_B : offMB;
        const unsigned int loB = condB ? offMB  : offA_B;
        rowsA[lev] = hiA | (loA << 16);
        rowsB[lev] = hiB | (loB << 16);

        if (condA) {
            rA = midA; offR_A = offMA;
            pkR_A0 = pkM_A0; pkR_A1 = pkM_A1;
        } else {
            lA = midA + 1; offA_A = offMA;
            pkA_A0 = pkM_A0; pkA_A1 = pkM_A1;
        }
        if (condB) {
            rB = midB; offR_B = offMB;
            pkR_B0 = pkM_B0; pkR_B1 = pkM_B1;
        } else {
            lB = midB + 1; offA_B = offMB;
            pkA_B0 = pkM_B0; pkA_B1 = pkM_B1;
        }
        if (lev < LEVELS - 1) {
            midA = condA ? (midA - step) : (midA + step);
            midB = condB ? (midB - step) : (midB + step);
        }
    }

    // ---- deferred value gather: ans = sum_lev w * (Pv[hi] - Pv[lo]) ----
    float4 aA0 = make_float4(0.f,0.f,0.f,0.f), aA1 = make_float4(0.f,0.f,0.f,0.f);
    float4 aB0 = make_float4(0.f,0.f,0.f,0.f), aB1 = make_float4(0.f,0.f,0.f,0.f);
    #pragma unroll
    for (int lev = 0; lev < LEVELS; ++lev) {
        const unsigned int pa = rowsA[lev];
        const unsigned int pb = rowsB[lev];
        const unsigned int hiA = pa & 0xFFFFu, loA = pa >> 16;
        const unsigned int hiB = pb & 0xFFFFu, loB = pb >> 16;
        const float4 hA0 = *(const float4*)(Vb + hiA);
        const float4 hA1 = *(const float4*)(Vb + hiA + 16);
        const float4 lA0 = *(const float4*)(Vb + loA);
        const float4 lA1 = *(const float4*)(Vb + loA + 16);
        fma4(aA0, hA0, lA0, wA[lev]);
        fma4(aA1, hA1, lA1, wA[lev]);
        const float4 hB0 = *(const float4*)(Vb + hiB);
        const float4 hB1 = *(const float4*)(Vb + hiB + 16);
        const float4 lB0 = *(const float4*)(Vb + loB);
        const float4 lB1 = *(const float4*)(Vb + loB + 16);
        fma4(aB0, hB0, lB0, wB[lev]);
        fma4(aB1, hB1, lB1, wB[lev]);
    }

    float* opA = out + ((size_t)b * S + sA) * DIM + c;
    float* opB = out + ((size_t)b * S + sB) * DIM + c;
    *(float4*)opA       = aA0;
    *(float4*)(opA + 4) = aA1;
    *(float4*)opB       = aB0;
    *(float4*)(opB + 4) = aB1;
}

extern "C" void kernel_launch(void* const* d_in, const int* in_sizes, int n_in,
                              void* d_out, int out_size, void* d_ws, size_t ws_size,
                              hipStream_t stream) {
    const float* q    = (const float*)d_in[0];
    const float* keys = (const float*)d_in[1];
    const float* vals = (const float*)d_in[2];
    const int*   vl   = (const int*)d_in[3];
    float* out = (float*)d_out;

    const int B = in_sizes[3];                 // 16
    const int S = in_sizes[0] / (B * DIM);     // 8192

    dim3 grid(S / QPB, B);
    segtree_attn_kernel<<<grid, THREADS, 0, stream>>>(q, keys, vals, vl, out, S);
}